// Round 5
// baseline (290.743 us; speedup 1.0000x reference)
//
#include <hip/hip_runtime.h>
#include <stdint.h>

typedef unsigned short us16;
typedef unsigned short us8  __attribute__((ext_vector_type(8)));
typedef unsigned short us4v __attribute__((ext_vector_type(4)));
typedef __bf16         bf16x8 __attribute__((ext_vector_type(8)));
typedef float          f32x4  __attribute__((ext_vector_type(4)));

__device__ __forceinline__ us16 f2bf(float f) {
    union { float f; unsigned int u; } c; c.f = f;
    unsigned int u = (c.u + 0x7fffu + ((c.u >> 16) & 1u)) >> 16;
    return (us16)u;
}
__device__ __forceinline__ float bf2f(us16 h) {
    union { unsigned int u; float f; } c; c.u = ((unsigned int)h) << 16;
    return c.f;
}

// async global->LDS, 16 B per lane; LDS dest = wave-uniform base + lane*16
__device__ __forceinline__ void async16(const us16* g, us16* l) {
    __builtin_amdgcn_global_load_lds(
        (const __attribute__((address_space(1))) unsigned int*)g,
        (__attribute__((address_space(3))) unsigned int*)l,
        16, 0, 0);
}

// ---------------------------------------------------------------------------
// Pipelined GEMM core:  C[n][m] = sum_k A[m][k]*B[n][k] (+bias), ldC = M
// 128x128 tile, BK=32, DOUBLE-buffered (2 x (A 8KB + B 8KB) = 32 KB LDS,
// 5 blocks/CU). Per iter: __syncthreads (drains loads issued a full compute
// phase ago) -> stage next tile into other buffer -> compute current.
// Staging: tile row = 32 halfs = 64 B; async16 chunk = 16 rows; lane l ->
// row l>>2, XOR-swizzled 16B-slot (l&3)^((l>>3)&3). Frag read slot =
// quad ^ ((l15>>1)&3) (i-invariant), 2-way banks = free.
// ---------------------------------------------------------------------------
__device__ __forceinline__ void stage32(const us16* Ap, const us16* Bp,
                                        us16* la, us16* lb, int K) {
    async16(Ap, la);
    async16(Ap + (size_t)16 * K, la + 16 * 32);
    async16(Bp, lb);
    async16(Bp + (size_t)16 * K, lb + 16 * 32);
}

__device__ __forceinline__ void compute32(const us16* La, const us16* Lb,
        f32x4 (&acc)[4][4], int wm, int wn, int l15, int fsl) {
    bf16x8 af[4], bfr[4];
#pragma unroll
    for (int i = 0; i < 4; i++) {
        af[i]  = *(const bf16x8*)(&La[(wm + i * 16 + l15) * 32 + fsl]);
        bfr[i] = *(const bf16x8*)(&Lb[(wn + i * 16 + l15) * 32 + fsl]);
    }
#pragma unroll
    for (int i = 0; i < 4; i++)
#pragma unroll
        for (int j = 0; j < 4; j++)
            acc[i][j] = __builtin_amdgcn_mfma_f32_16x16x32_bf16(af[i], bfr[j], acc[i][j], 0, 0, 0);
}

template <bool OUT_F32>
__device__ __forceinline__ void gemm_core(
        const us16* __restrict__ A, const us16* __restrict__ B,
        void* __restrict__ C, const float* __restrict__ bias, int biasmode,
        int M, int K, int x, int y, us16* ls) {
    const int m0 = x * 128, n0 = y * 128;
    const int tid = threadIdx.x;
    const int lane = tid & 63, wid = tid >> 6;
    const int l15 = lane & 15, quad = lane >> 4;
    const int wm = (wid & 1) * 64, wn = (wid >> 1) * 64;
    const int fsl = (quad ^ ((l15 >> 1) & 3)) * 8;

    f32x4 acc[4][4] = {};

    const int srow = lane >> 2;                       // row within 16-row chunk
    const int sc4 = (lane & 3) ^ ((lane >> 3) & 3);   // swizzled 16B slot
    const us16* Ap = A + (size_t)(m0 + wid * 32 + srow) * K + sc4 * 8;
    const us16* Bp = B + (size_t)(n0 + wid * 32 + srow) * K + sc4 * 8;
    us16* lA0 = ls + (wid * 32) * 32;                 // wave's staging dest
    us16* lB0 = ls + 4096 + (wid * 32) * 32;
    us16* lA1 = lA0 + 8192;
    us16* lB1 = lB0 + 8192;
    const us16* La0 = ls;                             // block-wide read bases
    const us16* Lb0 = ls + 4096;
    const us16* La1 = ls + 8192;
    const us16* Lb1 = ls + 12288;

    stage32(Ap, Bp, lA0, lB0, K);
    const int nIter = K >> 5;    // K is a multiple of 64 -> nIter even
    int kb = 32;
    for (int i = 0; i < nIter; i += 2) {
        __syncthreads();         // buf0 loads (in flight during prev compute) done
        if (i + 1 < nIter) stage32(Ap + kb, Bp + kb, lA1, lB1, K);
        compute32(La0, Lb0, acc, wm, wn, l15, fsl);
        __syncthreads();         // buf1 loads done; buf0 free to overwrite
        if (i + 2 < nIter) stage32(Ap + kb + 32, Bp + kb + 32, lA0, lB0, K);
        compute32(La1, Lb1, acc, wm, wn, l15, fsl);
        kb += 64;
    }

#pragma unroll
    for (int i = 0; i < 4; i++) {
        const int mb = m0 + wm + i * 16 + quad * 4;
        float b0 = 0.f, b1 = 0.f, b2 = 0.f, b3 = 0.f;
        if (biasmode == 1) {
            float4 bv4 = *(const float4*)(bias + mb);
            b0 = bv4.x; b1 = bv4.y; b2 = bv4.z; b3 = bv4.w;
        }
#pragma unroll
        for (int j = 0; j < 4; j++) {
            const int n = n0 + wn + j * 16 + l15;
            const float bn = (biasmode == 2) ? bias[n] : 0.0f;
            f32x4 v = acc[i][j];
            const float o0 = v[0] + b0 + bn, o1 = v[1] + b1 + bn;
            const float o2 = v[2] + b2 + bn, o3 = v[3] + b3 + bn;
            if (OUT_F32) {
                float4 st; st.x = o0; st.y = o1; st.z = o2; st.w = o3;
                *(float4*)((float*)C + (size_t)n * M + mb) = st;
            } else {
                us4v st = { f2bf(o0), f2bf(o1), f2bf(o2), f2bf(o3) };
                *(us4v*)((us16*)C + (size_t)n * M + mb) = st;
            }
        }
    }
}

// strip swizzle: lin in [0, gx*gy), strips of 4 m-panels (gx % 4 == 0).
// Same-XCD subsequences (stride 8) stay within a 4-A-panel strip -> L2 reuse.
__device__ __forceinline__ void strip_xy(int lin, int gy, int& x, int& y) {
    const int within = lin & (4 * gy - 1);   // gy is 8 or 16 (pow2)
    x = (lin / (4 * gy)) * 4 + (within & 3);
    y = within >> 2;
}

// ---------------------------------------------------------------------------
// prep: id<2048 -> transpose x [B][D][S] f32 -> XT [B][S][D] bf16 (64x64 tile)
//       id>=2048 -> convert Wq/Wk/Wv f32 -> Wb bf16 [3][1024][1024]
// ---------------------------------------------------------------------------
__global__ __launch_bounds__(256)
void prep(const float* __restrict__ x, us16* __restrict__ xt,
          const float* __restrict__ wq, const float* __restrict__ wk,
          const float* __restrict__ wv, us16* __restrict__ wb) {
    __shared__ us16 tile[64 * 65];
    const int id = blockIdx.x;
    const int t = threadIdx.x;
    if (id < 2048) {
        const int s0 = (id & 31) * 64, d0 = ((id >> 5) & 15) * 64, b = id >> 9;
        const float* xp = x + ((size_t)b * 1024 + d0) * 2048 + s0;
        const int r = t >> 4, c4 = t & 15;
#pragma unroll
        for (int i = 0; i < 4; i++) {
            float4 v = *(const float4*)(xp + (size_t)(r + 16 * i) * 2048 + c4 * 4);
            const int d = r + 16 * i;
            tile[(c4 * 4 + 0) * 65 + d] = f2bf(v.x);
            tile[(c4 * 4 + 1) * 65 + d] = f2bf(v.y);
            tile[(c4 * 4 + 2) * 65 + d] = f2bf(v.z);
            tile[(c4 * 4 + 3) * 65 + d] = f2bf(v.w);
        }
        __syncthreads();
        us16* op = xt + ((size_t)b * 2048 + s0) * 1024 + d0;
#pragma unroll
        for (int i = 0; i < 2; i++) {
            const int u = t + 256 * i;
            const int s = u >> 3, c8 = u & 7;
            us8 o;
#pragma unroll
            for (int j = 0; j < 8; j++) o[j] = tile[s * 65 + c8 * 8 + j];
            *(us8*)(op + (size_t)s * 1024 + c8 * 8) = o;
        }
    } else {
        const int cid = id - 2048;                  // 0..3071
        const int mb = cid >> 10;
        const float* src = (mb == 0) ? wq : (mb == 1) ? wk : wv;
        const size_t off = ((size_t)(cid & 1023) * 256 + t) * 4;
        float4 v = *(const float4*)(src + off);
        us4v o = { f2bf(v.x), f2bf(v.y), f2bf(v.z), f2bf(v.w) };
        *(us4v*)(wb + (size_t)mb * 1048576 + off) = o;
    }
}

// ---------------------------------------------------------------------------
// qkv: one dispatch, 1536 blocks.
//  id < 1024: Q/K.  z=id>>7 (0..3 Q, 4..7 K), lin=id&127, grid 8(m=e) x 16(n=s)
//  id >=1024: V.    z=(id-1024)>>7, grid 16(m=s) x 8(n=e) -> VT [e][s]
// ---------------------------------------------------------------------------
__global__ __launch_bounds__(256)
void qkv(const us16* __restrict__ Wb, const us16* __restrict__ XT,
         us16* __restrict__ Qb, us16* __restrict__ Kb, us16* __restrict__ VT,
         const float* __restrict__ bq, const float* __restrict__ bk,
         const float* __restrict__ bv) {
    __shared__ us16 ls[16384];
    const int id = blockIdx.x;
    const long long sXT = 2097152;   // S*D
    if (id < 1024) {
        const int z = id >> 7, zz = z & 3;
        const bool isK = z >= 4;
        int x, y; strip_xy(id & 127, 16, x, y);
        const us16* A = Wb + (isK ? 1048576 : 0);
        const us16* B = XT + (size_t)zz * sXT;
        us16* C = (isK ? Kb : Qb) + (size_t)zz * sXT;
        gemm_core<false>(A, B, (void*)C, isK ? bk : bq, 1, 1024, 1024, x, y, ls);
    } else {
        const int id2 = id - 1024;
        const int z = id2 >> 7;
        int x, y; strip_xy(id2 & 127, 8, x, y);
        const us16* A = XT + (size_t)z * sXT;
        us16* C = VT + (size_t)z * sXT;
        gemm_core<false>(A, Wb + 2097152, (void*)C, bv, 2, 2048, 1024, x, y, ls);
    }
}

// ---------------------------------------------------------------------------
// scores: S[b][s][t] = q_s.k_t  A=K (m=t), B=Q (n=s), grid (16,16,4)
// ---------------------------------------------------------------------------
__global__ __launch_bounds__(256)
void scores_k(const us16* __restrict__ Kb, const us16* __restrict__ Qb,
              us16* __restrict__ Sb) {
    __shared__ us16 ls[16384];
    const long long sXT = 2097152, sSS = 4194304;
    const int z = blockIdx.z;
    int x, y; strip_xy(blockIdx.x + 16 * blockIdx.y, 16, x, y);
    gemm_core<false>(Kb + (size_t)z * sXT, Qb + (size_t)z * sXT,
                     (void*)(Sb + (size_t)z * sSS), nullptr, 0,
                     2048, 1024, x, y, ls);
}

// ---------------------------------------------------------------------------
// out: out[b][s][e] = sum_t P[s][t] v[t][e]  A=VT (m=e), B=P (n=s), fp32 C
// grid (8,16,4)
// ---------------------------------------------------------------------------
__global__ __launch_bounds__(256)
void out_k(const us16* __restrict__ VT, const us16* __restrict__ Sb,
           float* __restrict__ out) {
    __shared__ us16 ls[16384];
    const long long sXT = 2097152, sSS = 4194304;
    const int z = blockIdx.z;
    int x, y; strip_xy(blockIdx.x + 8 * blockIdx.y, 16, x, y);
    gemm_core<true>(VT + (size_t)z * sXT, Sb + (size_t)z * sSS,
                    (void*)(out + (size_t)z * sXT), nullptr, 0,
                    1024, 2048, x, y, ls);
}

// ---------------------------------------------------------------------------
// softmax over rows of S [B*S][2048] bf16, scale 1/32, in place
// ---------------------------------------------------------------------------
__global__ __launch_bounds__(256)
void softmax_inplace(us16* __restrict__ S) {
    const float scale = 0.03125f;
    us16* p = S + (size_t)blockIdx.x * 2048;
    const int t = threadIdx.x;
    us8 v = *(const us8*)(p + t * 8);
    float x[8];
#pragma unroll
    for (int i = 0; i < 8; i++) x[i] = bf2f(v[i]) * scale;

    float m = x[0];
#pragma unroll
    for (int i = 1; i < 8; i++) m = fmaxf(m, x[i]);
#pragma unroll
    for (int off = 1; off < 64; off <<= 1) m = fmaxf(m, __shfl_xor(m, off, 64));
    __shared__ float red[4];
    __shared__ float red2[4];
    if ((t & 63) == 0) red[t >> 6] = m;
    __syncthreads();
    m = fmaxf(fmaxf(red[0], red[1]), fmaxf(red[2], red[3]));

    float s = 0.f;
#pragma unroll
    for (int i = 0; i < 8; i++) { x[i] = __expf(x[i] - m); s += x[i]; }
#pragma unroll
    for (int off = 1; off < 64; off <<= 1) s += __shfl_xor(s, off, 64);
    if ((t & 63) == 0) red2[t >> 6] = s;
    __syncthreads();
    s = red2[0] + red2[1] + red2[2] + red2[3];
    const float inv = 1.0f / s;

    us8 o;
#pragma unroll
    for (int i = 0; i < 8; i++) o[i] = f2bf(x[i] * inv);
    *(us8*)(p + t * 8) = o;
}

// ---------------------------------------------------------------------------
extern "C" void kernel_launch(void* const* d_in, const int* in_sizes, int n_in,
                              void* d_out, int out_size, void* d_ws, size_t ws_size,
                              hipStream_t stream) {
    const float* x  = (const float*)d_in[0];
    const float* Wq = (const float*)d_in[1];
    const float* bq = (const float*)d_in[2];
    const float* Wk = (const float*)d_in[3];
    const float* bk = (const float*)d_in[4];
    const float* Wv = (const float*)d_in[5];
    const float* bv = (const float*)d_in[6];
    float* out = (float*)d_out;
    char* ws = (char*)d_ws;

    const size_t SZ = 16777216;   // B*S*D bf16
    us16* Qb = (us16*)(ws);
    us16* Kb = (us16*)(ws + SZ);
    us16* VT = (us16*)(ws + 2 * SZ);            // [B][D][S]
    us16* XT = (us16*)(ws + 3 * SZ);            // [B][S][D]
    us16* Wb = (us16*)(ws + 4 * SZ);            // [3][1024][1024]
    us16* Sb = (us16*)(ws + 3 * SZ);            // scores/P [B][S][S], aliases dead XT/Wb

    dim3 blk(256, 1, 1);

    prep<<<dim3(5120, 1, 1), blk, 0, stream>>>(x, XT, Wq, Wk, Wv, Wb);
    qkv<<<dim3(1536, 1, 1), blk, 0, stream>>>(Wb, XT, Qb, Kb, VT, bq, bk, bv);
    scores_k<<<dim3(16, 16, 4), blk, 0, stream>>>(Kb, Qb, Sb);
    softmax_inplace<<<dim3(8192, 1, 1), blk, 0, stream>>>(Sb);
    out_k<<<dim3(8, 16, 4), blk, 0, stream>>>(VT, Sb, out);
}

// Round 6
// 246.285 us; speedup vs baseline: 1.1805x; 1.1805x over previous
//
#include <hip/hip_runtime.h>
#include <stdint.h>

typedef unsigned short us16;
typedef unsigned short us8  __attribute__((ext_vector_type(8)));
typedef unsigned short us4v __attribute__((ext_vector_type(4)));
typedef __bf16         bf16x8 __attribute__((ext_vector_type(8)));
typedef float          f32x4  __attribute__((ext_vector_type(4)));

__device__ __forceinline__ us16 f2bf(float f) {
    union { float f; unsigned int u; } c; c.f = f;
    unsigned int u = (c.u + 0x7fffu + ((c.u >> 16) & 1u)) >> 16;
    return (us16)u;
}
__device__ __forceinline__ float bf2f(us16 h) {
    union { unsigned int u; float f; } c; c.u = ((unsigned int)h) << 16;
    return c.f;
}

// async global->LDS, 16 B per lane; LDS dest = wave-uniform base + lane*16
__device__ __forceinline__ void async16(const us16* g, us16* l) {
    __builtin_amdgcn_global_load_lds(
        (const __attribute__((address_space(1))) unsigned int*)g,
        (__attribute__((address_space(3))) unsigned int*)l,
        16, 0, 0);
}

// ---------------------------------------------------------------------------
// GEMM core (R4-proven: BK=64, single-buffered, XOR-swizzle, 0 bank conflicts)
//  C[n][m] = sum_k A[m][k]*B[n][k], ldC = M.  128x128 tile, 4 waves 2x2,
//  4x4 mfma 16x16x32 bf16.
// EPI: 0 = bf16 store + bias[m]      (Q/K projections)
//      1 = bf16 store + bias[n]      (V projection -> VT)
//      2 = bf16 store of exp(acc/32) + atomicAdd row sums into L[n] (scores)
//      3 = f32 store of acc * (1/L[n])                              (out)
// ---------------------------------------------------------------------------
template <int EPI>
__device__ __forceinline__ void gemm_core(
        const us16* __restrict__ A, const us16* __restrict__ B,
        void* __restrict__ C, const float* __restrict__ bias,
        float* __restrict__ L,
        int M, int K, int x, int y, us16* lsA, us16* lsB) {
    const int m0 = x * 128, n0 = y * 128;
    const int tid = threadIdx.x;
    const int lane = tid & 63, wid = tid >> 6;
    const int l15 = lane & 15, quad = lane >> 4;
    const int wm = (wid & 1) * 64, wn = (wid >> 1) * 64;

    f32x4 acc[4][4] = {};

    // staging: wave w owns rows [w*32,w*32+32), lane l -> row l>>3,
    // swizzled 16B-chunk (l&7)^((l>>3)&7); LDS dest = base + lane*16 (HW).
    const int srow = wid * 32 + (lane >> 3);
    const int sc8 = (lane & 7) ^ ((lane >> 3) & 7);
    const us16* Ap = A + (size_t)(m0 + srow) * K + sc8 * 8;
    const us16* Bp = B + (size_t)(n0 + srow) * K + sc8 * 8;
    us16* ldsAw = &lsA[(wid * 32) * 64];
    us16* ldsBw = &lsB[(wid * 32) * 64];

    for (int kb = 0; kb < K; kb += 64) {
        __syncthreads();
#pragma unroll
        for (int c = 0; c < 4; c++) {
            async16(Ap + kb + (size_t)(c * 8) * K, ldsAw + c * 8 * 64);
            async16(Bp + kb + (size_t)(c * 8) * K, ldsBw + c * 8 * 64);
        }
        __syncthreads();
#pragma unroll
        for (int ks = 0; ks < 2; ks++) {
            bf16x8 af[4], bfr[4];
#pragma unroll
            for (int i = 0; i < 4; i++) {
                const int ra = wm + i * 16 + l15;
                const int rb = wn + i * 16 + l15;
                const int pa = ((ks * 4 + quad) ^ (ra & 7)) * 8;
                const int pb = ((ks * 4 + quad) ^ (rb & 7)) * 8;
                af[i]  = *(const bf16x8*)(&lsA[ra * 64 + pa]);
                bfr[i] = *(const bf16x8*)(&lsB[rb * 64 + pb]);
            }
#pragma unroll
            for (int i = 0; i < 4; i++)
#pragma unroll
                for (int j = 0; j < 4; j++)
                    acc[i][j] = __builtin_amdgcn_mfma_f32_16x16x32_bf16(af[i], bfr[j], acc[i][j], 0, 0, 0);
        }
    }

    if (EPI == 2) {
        // exp(scale*acc), bf16 store, per-row sums -> atomicAdd L[n]
        const float scale = 0.03125f;
        float rs[4] = {0.f, 0.f, 0.f, 0.f};
#pragma unroll
        for (int i = 0; i < 4; i++) {
            const int mb = m0 + wm + i * 16 + quad * 4;
#pragma unroll
            for (int j = 0; j < 4; j++) {
                const int n = n0 + wn + j * 16 + l15;
                f32x4 v = acc[i][j];
                const float e0 = __expf(v[0] * scale), e1 = __expf(v[1] * scale);
                const float e2 = __expf(v[2] * scale), e3 = __expf(v[3] * scale);
                rs[j] += (e0 + e1) + (e2 + e3);
                us4v st = { f2bf(e0), f2bf(e1), f2bf(e2), f2bf(e3) };
                *(us4v*)((us16*)C + (size_t)n * M + mb) = st;
            }
        }
        // reduce over quad (lanes sharing l15): lane bits 4,5
#pragma unroll
        for (int j = 0; j < 4; j++) {
            rs[j] += __shfl_xor(rs[j], 16, 64);
            rs[j] += __shfl_xor(rs[j], 32, 64);
        }
        if (quad == 0) {
#pragma unroll
            for (int j = 0; j < 4; j++)
                atomicAdd(&L[n0 + wn + j * 16 + l15], rs[j]);
        }
        return;
    }

#pragma unroll
    for (int i = 0; i < 4; i++) {
        const int mb = m0 + wm + i * 16 + quad * 4;
        float b0 = 0.f, b1 = 0.f, b2 = 0.f, b3 = 0.f;
        if (EPI == 0) {
            float4 bv4 = *(const float4*)(bias + mb);
            b0 = bv4.x; b1 = bv4.y; b2 = bv4.z; b3 = bv4.w;
        }
#pragma unroll
        for (int j = 0; j < 4; j++) {
            const int n = n0 + wn + j * 16 + l15;
            f32x4 v = acc[i][j];
            if (EPI == 3) {
                const float inv = 1.0f / L[n];
                float4 st;
                st.x = v[0] * inv; st.y = v[1] * inv;
                st.z = v[2] * inv; st.w = v[3] * inv;
                *(float4*)((float*)C + (size_t)n * M + mb) = st;
            } else {
                const float bn = (EPI == 1) ? bias[n] : 0.0f;
                us4v st = { f2bf(v[0] + b0 + bn), f2bf(v[1] + b1 + bn),
                            f2bf(v[2] + b2 + bn), f2bf(v[3] + b3 + bn) };
                *(us4v*)((us16*)C + (size_t)n * M + mb) = st;
            }
        }
    }
}

// strip swizzle: lin in [0, gx*gy), strips of 4 m-panels (gx % 4 == 0).
// Same-XCD subsequences (stride 8) stay within a 4-A-panel strip -> L2 reuse.
__device__ __forceinline__ void strip_xy(int lin, int gy, int& x, int& y) {
    const int within = lin & (4 * gy - 1);   // gy is 8 or 16 (pow2)
    x = (lin / (4 * gy)) * 4 + (within & 3);
    y = within >> 2;
}

// ---------------------------------------------------------------------------
// prep: id<2048 -> transpose x [B][D][S] f32 -> XT [B][S][D] bf16 (64x64 tile)
//       id>=2048 -> convert Wq/Wk/Wv f32 -> Wb bf16 [3][1024][1024]
// ---------------------------------------------------------------------------
__global__ __launch_bounds__(256)
void prep(const float* __restrict__ x, us16* __restrict__ xt,
          const float* __restrict__ wq, const float* __restrict__ wk,
          const float* __restrict__ wv, us16* __restrict__ wb) {
    __shared__ us16 tile[64 * 65];
    const int id = blockIdx.x;
    const int t = threadIdx.x;
    if (id < 2048) {
        const int s0 = (id & 31) * 64, d0 = ((id >> 5) & 15) * 64, b = id >> 9;
        const float* xp = x + ((size_t)b * 1024 + d0) * 2048 + s0;
        const int r = t >> 4, c4 = t & 15;
#pragma unroll
        for (int i = 0; i < 4; i++) {
            float4 v = *(const float4*)(xp + (size_t)(r + 16 * i) * 2048 + c4 * 4);
            const int d = r + 16 * i;
            tile[(c4 * 4 + 0) * 65 + d] = f2bf(v.x);
            tile[(c4 * 4 + 1) * 65 + d] = f2bf(v.y);
            tile[(c4 * 4 + 2) * 65 + d] = f2bf(v.z);
            tile[(c4 * 4 + 3) * 65 + d] = f2bf(v.w);
        }
        __syncthreads();
        us16* op = xt + ((size_t)b * 2048 + s0) * 1024 + d0;
#pragma unroll
        for (int i = 0; i < 2; i++) {
            const int u = t + 256 * i;
            const int s = u >> 3, c8 = u & 7;
            us8 o;
#pragma unroll
            for (int j = 0; j < 8; j++) o[j] = tile[s * 65 + c8 * 8 + j];
            *(us8*)(op + (size_t)s * 1024 + c8 * 8) = o;
        }
    } else {
        const int cid = id - 2048;                  // 0..3071
        const int mb = cid >> 10;
        const float* src = (mb == 0) ? wq : (mb == 1) ? wk : wv;
        const size_t off = ((size_t)(cid & 1023) * 256 + t) * 4;
        float4 v = *(const float4*)(src + off);
        us4v o = { f2bf(v.x), f2bf(v.y), f2bf(v.z), f2bf(v.w) };
        *(us4v*)(wb + (size_t)mb * 1048576 + off) = o;
    }
}

// ---------------------------------------------------------------------------
// qkv: one dispatch, 1536 blocks.
//  id < 1024: Q/K.  z=id>>7 (0..3 Q, 4..7 K), lin=id&127, grid 8(m=e) x 16(n=s)
//  id >=1024: V.    z=(id-1024)>>7, grid 16(m=s) x 8(n=e) -> VT [e][s]
// ---------------------------------------------------------------------------
__global__ __launch_bounds__(256)
void qkv(const us16* __restrict__ Wb, const us16* __restrict__ XT,
         us16* __restrict__ Qb, us16* __restrict__ Kb, us16* __restrict__ VT,
         const float* __restrict__ bq, const float* __restrict__ bk,
         const float* __restrict__ bv) {
    __shared__ us16 lsA[128 * 64];
    __shared__ us16 lsB[128 * 64];
    const int id = blockIdx.x;
    const long long sXT = 2097152;   // S*D
    if (id < 1024) {
        const int z = id >> 7, zz = z & 3;
        const bool isK = z >= 4;
        int x, y; strip_xy(id & 127, 16, x, y);
        const us16* A = Wb + (isK ? 1048576 : 0);
        const us16* B = XT + (size_t)zz * sXT;
        us16* C = (isK ? Kb : Qb) + (size_t)zz * sXT;
        gemm_core<0>(A, B, (void*)C, isK ? bk : bq, nullptr, 1024, 1024, x, y, lsA, lsB);
    } else {
        const int id2 = id - 1024;
        const int z = id2 >> 7;
        int x, y; strip_xy(id2 & 127, 8, x, y);
        const us16* A = XT + (size_t)z * sXT;
        us16* C = VT + (size_t)z * sXT;
        gemm_core<1>(A, Wb + 2097152, (void*)C, bv, nullptr, 2048, 1024, x, y, lsA, lsB);
    }
}

// ---------------------------------------------------------------------------
// scores: P~[b][s][t] = exp(q_s.k_t/32), plus L[b][s] = sum_t P~ (atomics)
// A=K (m=t), B=Q (n=s), grid (16,16,4)
// ---------------------------------------------------------------------------
__global__ __launch_bounds__(256)
void scores_k(const us16* __restrict__ Kb, const us16* __restrict__ Qb,
              us16* __restrict__ Sb, float* __restrict__ L) {
    __shared__ us16 lsA[128 * 64];
    __shared__ us16 lsB[128 * 64];
    const long long sXT = 2097152, sSS = 4194304;
    const int z = blockIdx.z;
    int x, y; strip_xy(blockIdx.x + 16 * blockIdx.y, 16, x, y);
    gemm_core<2>(Kb + (size_t)z * sXT, Qb + (size_t)z * sXT,
                 (void*)(Sb + (size_t)z * sSS), nullptr, L + z * 2048,
                 2048, 1024, x, y, lsA, lsB);
}

// ---------------------------------------------------------------------------
// out: out[b][s][e] = (sum_t P~[s][t] v[t][e]) / L[b][s]
// A=VT (m=e), B=P~ (n=s), fp32 C, grid (8,16,4)
// ---------------------------------------------------------------------------
__global__ __launch_bounds__(256)
void out_k(const us16* __restrict__ VT, const us16* __restrict__ Sb,
           float* __restrict__ L, float* __restrict__ out) {
    __shared__ us16 lsA[128 * 64];
    __shared__ us16 lsB[128 * 64];
    const long long sXT = 2097152, sSS = 4194304;
    const int z = blockIdx.z;
    int x, y; strip_xy(blockIdx.x + 8 * blockIdx.y, 16, x, y);
    gemm_core<3>(VT + (size_t)z * sXT, Sb + (size_t)z * sSS,
                 (void*)(out + (size_t)z * sXT), nullptr, L + z * 2048,
                 1024, 2048, x, y, lsA, lsB);
}

// ---------------------------------------------------------------------------
extern "C" void kernel_launch(void* const* d_in, const int* in_sizes, int n_in,
                              void* d_out, int out_size, void* d_ws, size_t ws_size,
                              hipStream_t stream) {
    const float* x  = (const float*)d_in[0];
    const float* Wq = (const float*)d_in[1];
    const float* bq = (const float*)d_in[2];
    const float* Wk = (const float*)d_in[3];
    const float* bk = (const float*)d_in[4];
    const float* Wv = (const float*)d_in[5];
    const float* bv = (const float*)d_in[6];
    float* out = (float*)d_out;
    char* ws = (char*)d_ws;

    const size_t SZ = 16777216;   // B*S*D bf16
    us16* Qb = (us16*)(ws);
    us16* Kb = (us16*)(ws + SZ);
    us16* VT = (us16*)(ws + 2 * SZ);            // [B][D][S]
    us16* XT = (us16*)(ws + 3 * SZ);            // [B][S][D]
    us16* Wb = (us16*)(ws + 4 * SZ);            // [3][1024][1024]
    us16* Sb = (us16*)(ws + 3 * SZ);            // P~ [B][S][S] in [48,80) MiB, aliases dead XT/Wb
    float* Lb = (float*)(ws + 5 * SZ);          // L [B][S] fp32 at 80 MiB

    dim3 blk(256, 1, 1);

    hipMemsetAsync(Lb, 0, 4 * 2048 * sizeof(float), stream);
    prep<<<dim3(5120, 1, 1), blk, 0, stream>>>(x, XT, Wq, Wk, Wv, Wb);
    qkv<<<dim3(1536, 1, 1), blk, 0, stream>>>(Wb, XT, Qb, Kb, VT, bq, bk, bv);
    scores_k<<<dim3(16, 16, 4), blk, 0, stream>>>(Kb, Qb, Sb, Lb);
    out_k<<<dim3(8, 16, 4), blk, 0, stream>>>(VT, Sb, Lb, out);
}